// Round 1
// baseline (930.713 us; speedup 1.0000x reference)
//
#include <hip/hip_runtime.h>
#include <hip/hip_bf16.h>
#include <math.h>

// ---------------------------------------------------------------------------
// GauntTensorProductAllParitiesS2Grid  (N=1024, MUL=128, C=128, lmax_in=3,
// lmax_out=6, grid 8x16=128, 3 parity configs)
//
// Pipeline:
//   K0 tables_kernel : Yin_t[g][16], Yow_t[g][52]  (transposed, k-contiguous,
//                      so hot-loop reads are thread-invariant -> s_load)
//   K1 fused123      : per (n,c) thread: stage1 (u-projection, both inputs)
//                      -> stage2 (to grid) -> mul -> stage3 (to k_out)
//                      writes z[ip][n][c][52] f32 into ws
//   K2 stage4        : per (n,d) thread: o[n,d,k] = sum_c z[n,c,k]*Wo[l(k),c,d]
// ---------------------------------------------------------------------------

#define PI_D 3.14159265358979323846

__device__ __constant__ int d_dummy; // (unused)

// l(k) tables
__device__ constexpr int LKIN16[16] = {0,1,1,1,2,2,2,2,2,3,3,3,3,3,3,3};
__device__ constexpr int LKOUT49[49] = {
  0,
  1,1,1,
  2,2,2,2,2,
  3,3,3,3,3,3,3,
  4,4,4,4,4,4,4,4,4,
  5,5,5,5,5,5,5,5,5,5,5,
  6,6,6,6,6,6,6,6,6,6,6,6,6};

// ---------------------------------------------------------------------------
// K0: spherical-harmonic tables. 1 block x 128 threads, thread = grid point g.
// g = b*16 + a  (beta-major, matching Y.reshape(K, B*A))
// ---------------------------------------------------------------------------
__global__ void tables_kernel(float* __restrict__ Yin_t, float* __restrict__ Yow_t)
{
  const int g = threadIdx.x;
  if (g >= 128) return;
  const int b = g >> 4;
  const int a = g & 15;

  // 8-point Gauss-Legendre nodes/weights on [-1,1] (ascending, = numpy leggauss)
  const double xb_[8] = {
    -0.9602898564975362, -0.7966664774136267, -0.5255324099163290, -0.1834346424956498,
     0.1834346424956498,  0.5255324099163290,  0.7966664774136267,  0.9602898564975362};
  const double wb_[8] = {
     0.10122853629037626, 0.22238103445337447, 0.31370664587788729, 0.36268378337836198,
     0.36268378337836198, 0.31370664587788729, 0.22238103445337447, 0.10122853629037626};

  const double x = xb_[b];
  const double s = sqrt(fmax(0.0, 1.0 - x * x));
  const double alpha = (2.0 * PI_D / 16.0) * (double)a;

  // associated Legendre (with Condon-Shortley as in the reference recurrence)
  double P[7][7];
  for (int l = 0; l < 7; ++l)
    for (int m = 0; m < 7; ++m) P[l][m] = 0.0;
  P[0][0] = 1.0;
  for (int m = 1; m <= 6; ++m) P[m][m] = -(double)(2 * m - 1) * s * P[m - 1][m - 1];
  for (int m = 0; m <= 5; ++m) P[m + 1][m] = (double)(2 * m + 1) * x * P[m][m];
  for (int m = 0; m <= 6; ++m)
    for (int l = m + 2; l <= 6; ++l)
      P[l][m] = ((double)(2 * l - 1) * x * P[l - 1][m] - (double)(l - 1 + m) * P[l - 2][m]) / (double)(l - m);

  const double qw = wb_[b] * (2.0 * PI_D / 16.0);

  for (int l = 0; l <= 6; ++l) {
    for (int m = -l; m <= l; ++m) {
      const int am = m < 0 ? -m : m;
      // (l-am)!/(l+am)! = prod_{j=l-am+1}^{l+am} 1/j
      double fr = 1.0;
      for (int j = l - am + 1; j <= l + am; ++j) fr /= (double)j;
      const double norm = sqrt((double)(2 * l + 1) / (4.0 * PI_D) * fr);
      double az;
      if (m > 0)      az = sqrt(2.0) * cos((double)m * alpha);
      else if (m == 0) az = 1.0;
      else            az = sqrt(2.0) * sin((double)am * alpha);
      const double Y = norm * P[l][am] * az;
      const int k = l * l + l + m;
      if (l <= 3) Yin_t[g * 16 + k] = (float)Y;
      Yow_t[g * 52 + k] = (float)(Y * qw);
    }
  }
  Yow_t[g * 52 + 49] = 0.f;
  Yow_t[g * 52 + 50] = 0.f;
  Yow_t[g * 52 + 51] = 0.f;
}

// ---------------------------------------------------------------------------
// K1: fused stage1+2+3.  grid = 1536 blocks (ip = blockIdx>>9), 256 threads.
// thread -> (n = nb*2 + tid>>7, c = tid&127).
// z layout: [ip][n][c][52] f32
// ---------------------------------------------------------------------------
template <int IP>
__device__ inline void fused123_body(
    int nb, int tid,
    const float* __restrict__ x1, const float* __restrict__ x2,
    const float* __restrict__ W1, const float* __restrict__ W2,
    const float* __restrict__ Yin_t, const float* __restrict__ Yow_t,
    float* __restrict__ zbuf)
{
  const int c = tid & 127;
  const int n = (nb << 1) | (tid >> 7);

  float c1a[16], c2a[16];
#pragma unroll
  for (int k = 0; k < 16; ++k) { c1a[k] = 0.f; c2a[k] = 0.f; }

  const float* w1b = W1 + (size_t)IP * 65536 + c;  // W_in1[IP][l][u][c]
  const float* w2b = W2 + (size_t)IP * 65536 + c;
  const float* xr1 = x1 + (size_t)n * 4096;        // x1[n][u][ch][k], 32 floats/u
  const float* xr2 = x2 + (size_t)n * 4096;

  for (int u = 0; u < 128; ++u) {
    float xa[32], xbv[32];
    const float4* p1 = reinterpret_cast<const float4*>(xr1 + u * 32);
    const float4* p2 = reinterpret_cast<const float4*>(xr2 + u * 32);
#pragma unroll
    for (int q = 0; q < 8; ++q) {
      float4 v1 = p1[q];
      xa[4 * q + 0] = v1.x; xa[4 * q + 1] = v1.y; xa[4 * q + 2] = v1.z; xa[4 * q + 3] = v1.w;
      float4 v2 = p2[q];
      xbv[4 * q + 0] = v2.x; xbv[4 * q + 1] = v2.y; xbv[4 * q + 2] = v2.z; xbv[4 * q + 3] = v2.w;
    }
    float w1v[4], w2v[4];
#pragma unroll
    for (int l = 0; l < 4; ++l) {
      w1v[l] = w1b[(l * 128 + u) * 128];
      w2v[l] = w2b[(l * 128 + u) * 128];
    }
#pragma unroll
    for (int k = 0; k < 16; ++k) {
      const int l = LKIN16[k];
      // pi_l = (1 - p*(-1)^l)/2 : p=+1 -> l&1 ; p=-1 -> (l&1)^1
      const int ch1 = (l & 1) ^ ((IP == 2) ? 1 : 0);  // p1 = (1,1,-1)[IP]
      const int ch2 = (l & 1) ^ ((IP == 1) ? 1 : 0);  // p2 = (1,-1,1)[IP]
      c1a[k] = fmaf(xa[ch1 * 16 + k], w1v[l], c1a[k]);
      c2a[k] = fmaf(xbv[ch2 * 16 + k], w2v[l], c2a[k]);
    }
  }

  const float ism = 0.08838834764831845f;  // 1/sqrt(128)
#pragma unroll
  for (int k = 0; k < 16; ++k) { c1a[k] *= ism; c2a[k] *= ism; }

  float zacc[49];
#pragma unroll
  for (int k = 0; k < 49; ++k) zacc[k] = 0.f;

  for (int g = 0; g < 128; ++g) {
    const float* yi = Yin_t + g * 16;   // thread-invariant address -> s_load
    const float* yo = Yow_t + g * 52;
    float g1 = 0.f, g2 = 0.f;
#pragma unroll
    for (int k = 0; k < 16; ++k) {
      const float y = yi[k];
      g1 = fmaf(c1a[k], y, g1);
      g2 = fmaf(c2a[k], y, g2);
    }
    const float pr = g1 * g2;
#pragma unroll
    for (int k = 0; k < 49; ++k) zacc[k] = fmaf(pr, yo[k], zacc[k]);
  }

  float* zp = zbuf + ((size_t)IP * 131072 + (size_t)n * 128 + c) * 52;
#pragma unroll
  for (int q = 0; q < 12; ++q) {
    float4 v;
    v.x = zacc[4 * q + 0]; v.y = zacc[4 * q + 1];
    v.z = zacc[4 * q + 2]; v.w = zacc[4 * q + 3];
    reinterpret_cast<float4*>(zp)[q] = v;
  }
  zp[48] = zacc[48];
}

__global__ __launch_bounds__(256) void fused123_kernel(
    const float* __restrict__ x1, const float* __restrict__ x2,
    const float* __restrict__ W1, const float* __restrict__ W2,
    const float* __restrict__ Yin_t, const float* __restrict__ Yow_t,
    float* __restrict__ zbuf)
{
  const int bid = blockIdx.x;
  const int ip = bid >> 9;     // 0..2 (wave-uniform)
  const int nb = bid & 511;    // 0..511
  const int tid = threadIdx.x;
  if (ip == 0)      fused123_body<0>(nb, tid, x1, x2, W1, W2, Yin_t, Yow_t, zbuf);
  else if (ip == 1) fused123_body<1>(nb, tid, x1, x2, W1, W2, Yin_t, Yow_t, zbuf);
  else              fused123_body<2>(nb, tid, x1, x2, W1, W2, Yin_t, Yow_t, zbuf);
}

// ---------------------------------------------------------------------------
// K2: stage4.  grid = 3 * 256 * 2 = 1536 blocks, 256 threads.
// block -> (i, nb (4 n's), db (64 d's)); thread -> (nl = tid>>6, dl = tid&63)
// o[n, i*6272 + d*49 + k] = (1/sqrt(C)) * sum_c z[i][n][c][k] * Wo[i][l(k)][c][d]
// ---------------------------------------------------------------------------
__global__ __launch_bounds__(256) void stage4_kernel(
    const float* __restrict__ zbuf, const float* __restrict__ Wout,
    float* __restrict__ out)
{
  const int bi = blockIdx.x;
  const int i  = bi >> 9;        // 0..2
  const int r  = bi & 511;
  const int nbk = r >> 1;        // 0..255
  const int db  = r & 1;         // 0..1
  const int tid = threadIdx.x;
  const int nl  = tid >> 6;      // 0..3
  const int dl  = tid & 63;      // 0..63
  const int n = nbk * 4 + nl;
  const int d = db * 64 + dl;

  float acc[49];
#pragma unroll
  for (int k = 0; k < 49; ++k) acc[k] = 0.f;

  const float* wb_ = Wout + (size_t)i * 114688 + d;               // Wout[i][l][c][d]
  const float* zb_ = zbuf + ((size_t)i * 131072 + (size_t)n * 128) * 52;

  for (int cc = 0; cc < 128; ++cc) {
    const float4* zr = reinterpret_cast<const float4*>(zb_ + (size_t)cc * 52);
    float zv[52];
#pragma unroll
    for (int q = 0; q < 13; ++q) {
      float4 v = zr[q];
      zv[4 * q + 0] = v.x; zv[4 * q + 1] = v.y;
      zv[4 * q + 2] = v.z; zv[4 * q + 3] = v.w;
    }
    float w[7];
#pragma unroll
    for (int l = 0; l < 7; ++l) w[l] = wb_[(l * 128 + cc) * 128];
#pragma unroll
    for (int k = 0; k < 49; ++k) acc[k] = fmaf(zv[k], w[LKOUT49[k]], acc[k]);
  }

  const float isc = 0.08838834764831845f;  // 1/sqrt(128)
  float* o = out + (size_t)n * 18816 + (size_t)i * 6272 + (size_t)d * 49;
#pragma unroll
  for (int k = 0; k < 49; ++k) o[k] = acc[k] * isc;
}

// ---------------------------------------------------------------------------
extern "C" void kernel_launch(void* const* d_in, const int* in_sizes, int n_in,
                              void* d_out, int out_size, void* d_ws, size_t ws_size,
                              hipStream_t stream)
{
  const float* x1 = (const float*)d_in[0];   // (1024,128,2,16)
  const float* x2 = (const float*)d_in[1];   // (1024,128,2,16)
  const float* W1 = (const float*)d_in[2];   // (3,4,128,128)
  const float* W2 = (const float*)d_in[3];   // (3,4,128,128)
  const float* Wo = (const float*)d_in[4];   // (3,7,128,128)
  float* out = (float*)d_out;                // (1024, 3*128*49)

  float* ws = (float*)d_ws;
  float* Yin_t = ws;            // 128*16 floats
  float* Yow_t = ws + 2048;     // 128*52 floats
  float* zbuf  = ws + 16384;    // 3*1024*128*52 floats (= 81.8 MB)

  tables_kernel<<<1, 128, 0, stream>>>(Yin_t, Yow_t);
  fused123_kernel<<<1536, 256, 0, stream>>>(x1, x2, W1, W2, Yin_t, Yow_t, zbuf);
  stage4_kernel<<<1536, 256, 0, stream>>>(zbuf, Wo, out);
}

// Round 2
// 554.223 us; speedup vs baseline: 1.6793x; 1.6793x over previous
//
#include <hip/hip_runtime.h>
#include <hip/hip_bf16.h>
#include <math.h>

// ---------------------------------------------------------------------------
// GauntTensorProductAllParitiesS2Grid  (N=1024, MUL=128, C=128, lmax_in=3,
// lmax_out=6, grid 8x16=128, 3 parity configs)
//
//   K0 tables_kernel : Yin_t[g][16], Yow_t[g][52] in ws
//   K1 fused123      : per (n,c) thread: stage1 (LDS-staged, channel-selected)
//                      -> stage2/3 (LDS-staged tables) -> z[ip][l][n][kk][c]
//   K2 stage4_gemm   : per (ip,l): GEMM (1024*(2l+1)) x 128(c) x 128(d),
//                      64x64 tiles, 4x4 per-thread, writes out directly
// ---------------------------------------------------------------------------

#define PI_D 3.14159265358979323846

__device__ __host__ constexpr int lof_in(int k)  { return k>=9?3 : k>=4?2 : k>=1?1 : 0; }
__device__ __host__ constexpr int lof_out(int k) { return k>=36?6 : k>=25?5 : k>=16?4 : k>=9?3 : k>=4?2 : k>=1?1 : 0; }

// ---------------------------------------------------------------------------
// K0: spherical-harmonic tables. 1 block x 128 threads, thread = grid point g.
// ---------------------------------------------------------------------------
__global__ void tables_kernel(float* __restrict__ Yin_t, float* __restrict__ Yow_t)
{
  const int g = threadIdx.x;
  if (g >= 128) return;
  const int b = g >> 4;
  const int a = g & 15;

  const double xb_[8] = {
    -0.9602898564975362, -0.7966664774136267, -0.5255324099163290, -0.1834346424956498,
     0.1834346424956498,  0.5255324099163290,  0.7966664774136267,  0.9602898564975362};
  const double wb_[8] = {
     0.10122853629037626, 0.22238103445337447, 0.31370664587788729, 0.36268378337836198,
     0.36268378337836198, 0.31370664587788729, 0.22238103445337447, 0.10122853629037626};

  const double x = xb_[b];
  const double s = sqrt(fmax(0.0, 1.0 - x * x));
  const double alpha = (2.0 * PI_D / 16.0) * (double)a;

  double P[7][7];
  for (int l = 0; l < 7; ++l)
    for (int m = 0; m < 7; ++m) P[l][m] = 0.0;
  P[0][0] = 1.0;
  for (int m = 1; m <= 6; ++m) P[m][m] = -(double)(2 * m - 1) * s * P[m - 1][m - 1];
  for (int m = 0; m <= 5; ++m) P[m + 1][m] = (double)(2 * m + 1) * x * P[m][m];
  for (int m = 0; m <= 6; ++m)
    for (int l = m + 2; l <= 6; ++l)
      P[l][m] = ((double)(2 * l - 1) * x * P[l - 1][m] - (double)(l - 1 + m) * P[l - 2][m]) / (double)(l - m);

  const double qw = wb_[b] * (2.0 * PI_D / 16.0);

  for (int l = 0; l <= 6; ++l) {
    for (int m = -l; m <= l; ++m) {
      const int am = m < 0 ? -m : m;
      double fr = 1.0;
      for (int j = l - am + 1; j <= l + am; ++j) fr /= (double)j;
      const double norm = sqrt((double)(2 * l + 1) / (4.0 * PI_D) * fr);
      double az;
      if (m > 0)       az = sqrt(2.0) * cos((double)m * alpha);
      else if (m == 0) az = 1.0;
      else             az = sqrt(2.0) * sin((double)am * alpha);
      const double Y = norm * P[l][am] * az;
      const int k = l * l + l + m;
      if (l <= 3) Yin_t[g * 16 + k] = (float)Y;
      Yow_t[g * 52 + k] = (float)(Y * qw);
    }
  }
  Yow_t[g * 52 + 49] = 0.f;
  Yow_t[g * 52 + 50] = 0.f;
  Yow_t[g * 52 + 51] = 0.f;
}

// ---------------------------------------------------------------------------
// K1: fused stage1+2+3.  1536 blocks (ip = bid>>9), 256 threads.
// thread -> (n = nb*2 + tid>>7, c = tid&127)
// LDS (34 KB union):
//   stage1 : xsel[inp(2)][nn(2)][u(32)][k(16)]  (2048 floats / u-chunk)
//   stage23: yin[128*16] @0, yow[128*52] @2048
// z layout: [ip][l][n][kk][c]   (group base l*l*131072 within ip slice)
// ---------------------------------------------------------------------------
template <int IP>
__device__ __forceinline__ void fused123_body(
    int nb, int tid, float* lds,
    const float* __restrict__ x1, const float* __restrict__ x2,
    const float* __restrict__ W1, const float* __restrict__ W2,
    const float* __restrict__ Yin_t, const float* __restrict__ Yow_t,
    float* __restrict__ zbuf)
{
  const int c  = tid & 127;
  const int nn = tid >> 7;
  const int n  = nb * 2 + nn;

  float c1a[16], c2a[16];
#pragma unroll
  for (int k = 0; k < 16; ++k) { c1a[k] = 0.f; c2a[k] = 0.f; }

  const float* w1b = W1 + IP * 65536 + c;   // W[ip][l][u][c]
  const float* w2b = W2 + IP * 65536 + c;

  for (int uc = 0; uc < 4; ++uc) {
    __syncthreads();
    // stage 2048 channel-selected floats: e = [inp][nns][u][k]
#pragma unroll
    for (int i = 0; i < 8; ++i) {
      const int e   = tid + 256 * i;
      const int inp = e >> 10;
      const int r   = e & 1023;
      const int nns = r >> 9;
      const int u   = (r >> 4) & 31;
      const int k   = r & 15;
      const int l   = lof_in(k);
      const int flip = (inp == 0) ? ((IP == 2) ? 1 : 0) : ((IP == 1) ? 1 : 0);
      const int ch  = (l & 1) ^ flip;
      const float* src = (inp == 0) ? x1 : x2;
      lds[e] = src[(size_t)(nb * 2 + nns) * 4096 + uc * 1024 + u * 32 + ch * 16 + k];
    }
    __syncthreads();
    for (int uu = 0; uu < 32; ++uu) {
      const int u = uc * 32 + uu;
      float w1v[4], w2v[4];
#pragma unroll
      for (int l = 0; l < 4; ++l) {
        w1v[l] = w1b[(l * 128 + u) * 128];
        w2v[l] = w2b[(l * 128 + u) * 128];
      }
      const float4* xs1 = (const float4*)&lds[nn * 512 + uu * 16];
      const float4* xs2 = (const float4*)&lds[1024 + nn * 512 + uu * 16];
      const float4 A0 = xs1[0], A1 = xs1[1], A2 = xs1[2], A3 = xs1[3];
      const float4 B0 = xs2[0], B1 = xs2[1], B2 = xs2[2], B3 = xs2[3];
      // l(k): k0->0, k1-3->1, k4-8->2, k9-15->3
      c1a[0]  = fmaf(A0.x, w1v[0], c1a[0]);
      c1a[1]  = fmaf(A0.y, w1v[1], c1a[1]);
      c1a[2]  = fmaf(A0.z, w1v[1], c1a[2]);
      c1a[3]  = fmaf(A0.w, w1v[1], c1a[3]);
      c1a[4]  = fmaf(A1.x, w1v[2], c1a[4]);
      c1a[5]  = fmaf(A1.y, w1v[2], c1a[5]);
      c1a[6]  = fmaf(A1.z, w1v[2], c1a[6]);
      c1a[7]  = fmaf(A1.w, w1v[2], c1a[7]);
      c1a[8]  = fmaf(A2.x, w1v[2], c1a[8]);
      c1a[9]  = fmaf(A2.y, w1v[3], c1a[9]);
      c1a[10] = fmaf(A2.z, w1v[3], c1a[10]);
      c1a[11] = fmaf(A2.w, w1v[3], c1a[11]);
      c1a[12] = fmaf(A3.x, w1v[3], c1a[12]);
      c1a[13] = fmaf(A3.y, w1v[3], c1a[13]);
      c1a[14] = fmaf(A3.z, w1v[3], c1a[14]);
      c1a[15] = fmaf(A3.w, w1v[3], c1a[15]);

      c2a[0]  = fmaf(B0.x, w2v[0], c2a[0]);
      c2a[1]  = fmaf(B0.y, w2v[1], c2a[1]);
      c2a[2]  = fmaf(B0.z, w2v[1], c2a[2]);
      c2a[3]  = fmaf(B0.w, w2v[1], c2a[3]);
      c2a[4]  = fmaf(B1.x, w2v[2], c2a[4]);
      c2a[5]  = fmaf(B1.y, w2v[2], c2a[5]);
      c2a[6]  = fmaf(B1.z, w2v[2], c2a[6]);
      c2a[7]  = fmaf(B1.w, w2v[2], c2a[7]);
      c2a[8]  = fmaf(B2.x, w2v[2], c2a[8]);
      c2a[9]  = fmaf(B2.y, w2v[3], c2a[9]);
      c2a[10] = fmaf(B2.z, w2v[3], c2a[10]);
      c2a[11] = fmaf(B2.w, w2v[3], c2a[11]);
      c2a[12] = fmaf(B3.x, w2v[3], c2a[12]);
      c2a[13] = fmaf(B3.y, w2v[3], c2a[13]);
      c2a[14] = fmaf(B3.z, w2v[3], c2a[14]);
      c2a[15] = fmaf(B3.w, w2v[3], c2a[15]);
    }
  }

  const float ism = 0.08838834764831845f;  // 1/sqrt(128)
#pragma unroll
  for (int k = 0; k < 16; ++k) { c1a[k] *= ism; c2a[k] *= ism; }

  // load tables into LDS
  __syncthreads();
  for (int i = tid; i < 8704; i += 256)
    lds[i] = (i < 2048) ? Yin_t[i] : Yow_t[i - 2048];
  __syncthreads();

  float zacc[49];
#pragma unroll
  for (int k = 0; k < 49; ++k) zacc[k] = 0.f;

  for (int g = 0; g < 128; ++g) {
    const float4* yi = (const float4*)&lds[g * 16];
    const float4 y0 = yi[0], y1 = yi[1], y2 = yi[2], y3 = yi[3];
    float s0 = fmaf(c1a[0], y0.x, c1a[1] * y0.y);
    float s1 = fmaf(c1a[2], y0.z, c1a[3] * y0.w);
    float s2 = fmaf(c1a[4], y1.x, c1a[5] * y1.y);
    float s3 = fmaf(c1a[6], y1.z, c1a[7] * y1.w);
    float s4 = fmaf(c1a[8], y2.x, c1a[9] * y2.y);
    float s5 = fmaf(c1a[10], y2.z, c1a[11] * y2.w);
    float s6 = fmaf(c1a[12], y3.x, c1a[13] * y3.y);
    float s7 = fmaf(c1a[14], y3.z, c1a[15] * y3.w);
    const float g1 = ((s0 + s1) + (s2 + s3)) + ((s4 + s5) + (s6 + s7));
    float t0 = fmaf(c2a[0], y0.x, c2a[1] * y0.y);
    float t1 = fmaf(c2a[2], y0.z, c2a[3] * y0.w);
    float t2 = fmaf(c2a[4], y1.x, c2a[5] * y1.y);
    float t3 = fmaf(c2a[6], y1.z, c2a[7] * y1.w);
    float t4 = fmaf(c2a[8], y2.x, c2a[9] * y2.y);
    float t5 = fmaf(c2a[10], y2.z, c2a[11] * y2.w);
    float t6 = fmaf(c2a[12], y3.x, c2a[13] * y3.y);
    float t7 = fmaf(c2a[14], y3.z, c2a[15] * y3.w);
    const float g2 = ((t0 + t1) + (t2 + t3)) + ((t4 + t5) + (t6 + t7));
    const float pr = g1 * g2;

    const float4* yo = (const float4*)&lds[2048 + g * 52];
#pragma unroll
    for (int q = 0; q < 12; ++q) {
      const float4 v = yo[q];
      zacc[4 * q + 0] = fmaf(pr, v.x, zacc[4 * q + 0]);
      zacc[4 * q + 1] = fmaf(pr, v.y, zacc[4 * q + 1]);
      zacc[4 * q + 2] = fmaf(pr, v.z, zacc[4 * q + 2]);
      zacc[4 * q + 3] = fmaf(pr, v.w, zacc[4 * q + 3]);
    }
    zacc[48] = fmaf(pr, lds[2048 + g * 52 + 48], zacc[48]);
  }

  // store z[ip][l][n][kk][c]
  const size_t zb = (size_t)IP * 6422528 + (size_t)c;
#pragma unroll
  for (int k = 0; k < 49; ++k) {
    const int l  = lof_out(k);
    const int kg = 2 * l + 1;
    const int kk = k - l * l;
    zbuf[zb + (size_t)(l * l) * 131072 + (size_t)(n * kg + kk) * 128] = zacc[k];
  }
}

__global__ __launch_bounds__(256, 3) void fused123_kernel(
    const float* __restrict__ x1, const float* __restrict__ x2,
    const float* __restrict__ W1, const float* __restrict__ W2,
    const float* __restrict__ Yin_t, const float* __restrict__ Yow_t,
    float* __restrict__ zbuf)
{
  __shared__ float lds[8704];   // 34 KB
  const int bid = blockIdx.x;
  const int ip = bid >> 9;
  const int nb = bid & 511;
  const int tid = threadIdx.x;
  if (ip == 0)      fused123_body<0>(nb, tid, lds, x1, x2, W1, W2, Yin_t, Yow_t, zbuf);
  else if (ip == 1) fused123_body<1>(nb, tid, lds, x1, x2, W1, W2, Yin_t, Yow_t, zbuf);
  else              fused123_body<2>(nb, tid, lds, x1, x2, W1, W2, Yin_t, Yow_t, zbuf);
}

// ---------------------------------------------------------------------------
// K2: stage4 as GEMM.  grid = 3 * 49 * 32 = 4704 blocks, 256 threads.
// Per (ip,l): C[m][d] = sum_c A[m][c]*B[c][d],  m=(n*kg+kk), M=1024*kg
// tiles: 64x64, per-thread 4x4.  Epilogue -> out[n][ip*6272 + d*49 + l*l+kk]
// ---------------------------------------------------------------------------
__global__ __launch_bounds__(256, 4) void stage4_gemm(
    const float* __restrict__ zbuf, const float* __restrict__ Wout,
    float* __restrict__ out)
{
  __shared__ float As[64 * 36];  // [m][c], stride 36
  __shared__ float Bs[32 * 68];  // [c][d], stride 68

  const int bid = blockIdx.x;
  const int ip = bid / 1568;
  const int r  = bid - ip * 1568;
  const int w  = r >> 5;              // 0..48  (k-like index; l-groups at l^2)
  const int l  = lof_out(w);
  const int kg = 2 * l + 1;
  const int tt = r - 32 * l * l;      // tile index within (ip,l): 0..kg*32-1
  const int tm = tt >> 1;
  const int td = tt & 1;

  const float* A = zbuf + (size_t)ip * 6422528 + (size_t)(l * l) * 131072 + (size_t)tm * 64 * 128;
  const float* B = Wout + (size_t)ip * 114688 + (size_t)l * 16384 + td * 64;

  const int t  = threadIdx.x;
  const int tx = t & 15;
  const int ty = t >> 4;

  float acc[16];
#pragma unroll
  for (int i = 0; i < 16; ++i) acc[i] = 0.f;

  for (int cc = 0; cc < 4; ++cc) {
    __syncthreads();
#pragma unroll
    for (int i = 0; i < 2; ++i) {
      const int f = t + 256 * i;
      const int rr = f >> 3, c4 = f & 7;
      *(float4*)&As[rr * 36 + c4 * 4] =
          *(const float4*)&A[(size_t)rr * 128 + cc * 32 + c4 * 4];
    }
#pragma unroll
    for (int i = 0; i < 2; ++i) {
      const int f = t + 256 * i;
      const int rr = f >> 4, c4 = f & 15;
      *(float4*)&Bs[rr * 68 + c4 * 4] =
          *(const float4*)&B[(size_t)(cc * 32 + rr) * 128 + c4 * 4];
    }
    __syncthreads();
#pragma unroll
    for (int c = 0; c < 32; ++c) {
      const float a0 = As[(ty * 4 + 0) * 36 + c];
      const float a1 = As[(ty * 4 + 1) * 36 + c];
      const float a2 = As[(ty * 4 + 2) * 36 + c];
      const float a3 = As[(ty * 4 + 3) * 36 + c];
      const float4 b = *(const float4*)&Bs[c * 68 + tx * 4];
      acc[0]  = fmaf(a0, b.x, acc[0]);
      acc[1]  = fmaf(a0, b.y, acc[1]);
      acc[2]  = fmaf(a0, b.z, acc[2]);
      acc[3]  = fmaf(a0, b.w, acc[3]);
      acc[4]  = fmaf(a1, b.x, acc[4]);
      acc[5]  = fmaf(a1, b.y, acc[5]);
      acc[6]  = fmaf(a1, b.z, acc[6]);
      acc[7]  = fmaf(a1, b.w, acc[7]);
      acc[8]  = fmaf(a2, b.x, acc[8]);
      acc[9]  = fmaf(a2, b.y, acc[9]);
      acc[10] = fmaf(a2, b.z, acc[10]);
      acc[11] = fmaf(a2, b.w, acc[11]);
      acc[12] = fmaf(a3, b.x, acc[12]);
      acc[13] = fmaf(a3, b.y, acc[13]);
      acc[14] = fmaf(a3, b.z, acc[14]);
      acc[15] = fmaf(a3, b.w, acc[15]);
    }
  }

  const float isc = 0.08838834764831845f;  // 1/sqrt(128)
  const int d0 = td * 64 + tx * 4;
#pragma unroll
  for (int i = 0; i < 4; ++i) {
    const int m  = tm * 64 + ty * 4 + i;
    const int nn = m / kg;
    const int kk = m - nn * kg;
    float* orow = out + (size_t)nn * 18816 + ip * 6272 + (l * l + kk) + (size_t)d0 * 49;
    orow[0]   = acc[i * 4 + 0] * isc;
    orow[49]  = acc[i * 4 + 1] * isc;
    orow[98]  = acc[i * 4 + 2] * isc;
    orow[147] = acc[i * 4 + 3] * isc;
  }
}

// ---------------------------------------------------------------------------
extern "C" void kernel_launch(void* const* d_in, const int* in_sizes, int n_in,
                              void* d_out, int out_size, void* d_ws, size_t ws_size,
                              hipStream_t stream)
{
  const float* x1 = (const float*)d_in[0];   // (1024,128,2,16)
  const float* x2 = (const float*)d_in[1];   // (1024,128,2,16)
  const float* W1 = (const float*)d_in[2];   // (3,4,128,128)
  const float* W2 = (const float*)d_in[3];   // (3,4,128,128)
  const float* Wo = (const float*)d_in[4];   // (3,7,128,128)
  float* out = (float*)d_out;                // (1024, 3*128*49)

  float* ws = (float*)d_ws;
  float* Yin_t = ws;            // 128*16
  float* Yow_t = ws + 2048;     // 128*52
  float* zbuf  = ws + 16384;    // 3*49*1024*128 floats = 77.1 MB

  tables_kernel<<<1, 128, 0, stream>>>(Yin_t, Yow_t);
  fused123_kernel<<<1536, 256, 0, stream>>>(x1, x2, W1, W2, Yin_t, Yow_t, zbuf);
  stage4_gemm<<<4704, 256, 0, stream>>>(zbuf, Wo, out);
}

// Round 3
// 416.383 us; speedup vs baseline: 2.2352x; 1.3310x over previous
//
#include <hip/hip_runtime.h>
#include <hip/hip_bf16.h>
#include <math.h>

// ---------------------------------------------------------------------------
// GauntTensorProductAllParitiesS2Grid  (N=1024, MUL=128, C=128, lmax_in=3,
// lmax_out=6, grid 8x16=128, 3 parity configs)
//
//   K0a tables_kernel : YinH f16 [128g][16k], YowH f16 [64kout][128g] (padded)
//   K0b prep_wot      : WoTH f16 [3][7][128d][128c]  (transpose of W_out)
//   K1  stage1_kernel : fp32 VALU u-projection -> c1H/c2H f16 [ip][n][c][16]
//   K2  fused23_kernel: per (ip,n): MFMA GEMM1 (xYin), P=G1*G2, LDS-transpose,
//                       MFMA GEMM2 (xYowT) -> zH f16 [ip][kout49][n][c]
//   K3  stage4_mfma   : per (ip,k49,nblk): MFMA GEMM over c with WoT -> out
// ---------------------------------------------------------------------------

#define PI_D 3.14159265358979323846

using short8 = __attribute__((ext_vector_type(8))) short;
using f32x4  = __attribute__((ext_vector_type(4))) float;

__device__ __host__ constexpr int lof_in(int k)  { return k>=9?3 : k>=4?2 : k>=1?1 : 0; }
__device__ __host__ constexpr int lof_out(int k) { return k>=36?6 : k>=25?5 : k>=16?4 : k>=9?3 : k>=4?2 : k>=1?1 : 0; }

__device__ __forceinline__ unsigned short f2h(float f) {
  _Float16 h = (_Float16)f;
  return __builtin_bit_cast(unsigned short, h);
}

// ---------------------------------------------------------------------------
// K0a: spherical-harmonic tables (f16). 1 block x 128 threads, thread = g.
// ---------------------------------------------------------------------------
__global__ void tables_kernel(unsigned short* __restrict__ YinH,
                              unsigned short* __restrict__ YowH)
{
  const int g = threadIdx.x;
  if (g >= 128) return;
  const int b = g >> 4;
  const int a = g & 15;

  const double xb_[8] = {
    -0.9602898564975362, -0.7966664774136267, -0.5255324099163290, -0.1834346424956498,
     0.1834346424956498,  0.5255324099163290,  0.7966664774136267,  0.9602898564975362};
  const double wb_[8] = {
     0.10122853629037626, 0.22238103445337447, 0.31370664587788729, 0.36268378337836198,
     0.36268378337836198, 0.31370664587788729, 0.22238103445337447, 0.10122853629037626};

  const double x = xb_[b];
  const double s = sqrt(fmax(0.0, 1.0 - x * x));
  const double alpha = (2.0 * PI_D / 16.0) * (double)a;

  double P[7][7];
  for (int l = 0; l < 7; ++l)
    for (int m = 0; m < 7; ++m) P[l][m] = 0.0;
  P[0][0] = 1.0;
  for (int m = 1; m <= 6; ++m) P[m][m] = -(double)(2 * m - 1) * s * P[m - 1][m - 1];
  for (int m = 0; m <= 5; ++m) P[m + 1][m] = (double)(2 * m + 1) * x * P[m][m];
  for (int m = 0; m <= 6; ++m)
    for (int l = m + 2; l <= 6; ++l)
      P[l][m] = ((double)(2 * l - 1) * x * P[l - 1][m] - (double)(l - 1 + m) * P[l - 2][m]) / (double)(l - m);

  const double qw = wb_[b] * (2.0 * PI_D / 16.0);

  for (int l = 0; l <= 6; ++l) {
    for (int m = -l; m <= l; ++m) {
      const int am = m < 0 ? -m : m;
      double fr = 1.0;
      for (int j = l - am + 1; j <= l + am; ++j) fr /= (double)j;
      const double norm = sqrt((double)(2 * l + 1) / (4.0 * PI_D) * fr);
      double az;
      if (m > 0)       az = sqrt(2.0) * cos((double)m * alpha);
      else if (m == 0) az = 1.0;
      else             az = sqrt(2.0) * sin((double)am * alpha);
      const double Y = norm * P[l][am] * az;
      const int k = l * l + l + m;
      if (l <= 3) YinH[g * 16 + k] = f2h((float)Y);
      YowH[k * 128 + g] = f2h((float)(Y * qw));
    }
  }
  for (int k = 49; k < 64; ++k) YowH[k * 128 + g] = 0;
}

// ---------------------------------------------------------------------------
// K0b: WoTH[ip][l][d][c] = f16(W_out[ip][l][c][d]).  1344 blocks x 256.
// ---------------------------------------------------------------------------
__global__ void prep_wot(const float* __restrict__ Wo, unsigned short* __restrict__ WoTH)
{
  const int e = blockIdx.x * 256 + threadIdx.x;   // < 344064
  const int c = e & 127;
  const int d = (e >> 7) & 127;
  const int r = e >> 14;                          // ip*7 + l, 0..20
  WoTH[((size_t)r * 128 + d) * 128 + c] = f2h(Wo[((size_t)r * 128 + c) * 128 + d]);
}

// ---------------------------------------------------------------------------
// K1: stage1 (fp32).  1536 blocks (ip = bid>>9), 256 threads.
// thread -> (n = nb*2 + tid>>7, c = tid&127);  LDS x-staging w/ channel select.
// out: c1H/c2H f16 [ip][n][c][16]
// ---------------------------------------------------------------------------
template <int IP>
__device__ __forceinline__ void stage1_body(
    int nb, int tid, float* lds,
    const float* __restrict__ x1, const float* __restrict__ x2,
    const float* __restrict__ W1, const float* __restrict__ W2,
    unsigned short* __restrict__ c1H, unsigned short* __restrict__ c2H)
{
  const int c  = tid & 127;
  const int nn = tid >> 7;
  const int n  = nb * 2 + nn;

  float c1a[16], c2a[16];
#pragma unroll
  for (int k = 0; k < 16; ++k) { c1a[k] = 0.f; c2a[k] = 0.f; }

  const float* w1b = W1 + IP * 65536 + c;   // W[ip][l][u][c]
  const float* w2b = W2 + IP * 65536 + c;

  for (int uc = 0; uc < 4; ++uc) {
    __syncthreads();
#pragma unroll
    for (int i = 0; i < 8; ++i) {
      const int e   = tid + 256 * i;
      const int inp = e >> 10;
      const int r   = e & 1023;
      const int nns = r >> 9;
      const int u   = (r >> 4) & 31;
      const int k   = r & 15;
      const int l   = lof_in(k);
      const int flip = (inp == 0) ? ((IP == 2) ? 1 : 0) : ((IP == 1) ? 1 : 0);
      const int ch  = (l & 1) ^ flip;
      const float* src = (inp == 0) ? x1 : x2;
      lds[e] = src[(size_t)(nb * 2 + nns) * 4096 + uc * 1024 + u * 32 + ch * 16 + k];
    }
    __syncthreads();
    for (int uu = 0; uu < 32; ++uu) {
      const int u = uc * 32 + uu;
      float w1v[4], w2v[4];
#pragma unroll
      for (int l = 0; l < 4; ++l) {
        w1v[l] = w1b[(l * 128 + u) * 128];
        w2v[l] = w2b[(l * 128 + u) * 128];
      }
      const float4* xs1 = (const float4*)&lds[nn * 512 + uu * 16];
      const float4* xs2 = (const float4*)&lds[1024 + nn * 512 + uu * 16];
      const float4 A0 = xs1[0], A1 = xs1[1], A2 = xs1[2], A3 = xs1[3];
      const float4 B0 = xs2[0], B1 = xs2[1], B2 = xs2[2], B3 = xs2[3];
      c1a[0]  = fmaf(A0.x, w1v[0], c1a[0]);
      c1a[1]  = fmaf(A0.y, w1v[1], c1a[1]);
      c1a[2]  = fmaf(A0.z, w1v[1], c1a[2]);
      c1a[3]  = fmaf(A0.w, w1v[1], c1a[3]);
      c1a[4]  = fmaf(A1.x, w1v[2], c1a[4]);
      c1a[5]  = fmaf(A1.y, w1v[2], c1a[5]);
      c1a[6]  = fmaf(A1.z, w1v[2], c1a[6]);
      c1a[7]  = fmaf(A1.w, w1v[2], c1a[7]);
      c1a[8]  = fmaf(A2.x, w1v[2], c1a[8]);
      c1a[9]  = fmaf(A2.y, w1v[3], c1a[9]);
      c1a[10] = fmaf(A2.z, w1v[3], c1a[10]);
      c1a[11] = fmaf(A2.w, w1v[3], c1a[11]);
      c1a[12] = fmaf(A3.x, w1v[3], c1a[12]);
      c1a[13] = fmaf(A3.y, w1v[3], c1a[13]);
      c1a[14] = fmaf(A3.z, w1v[3], c1a[14]);
      c1a[15] = fmaf(A3.w, w1v[3], c1a[15]);

      c2a[0]  = fmaf(B0.x, w2v[0], c2a[0]);
      c2a[1]  = fmaf(B0.y, w2v[1], c2a[1]);
      c2a[2]  = fmaf(B0.z, w2v[1], c2a[2]);
      c2a[3]  = fmaf(B0.w, w2v[1], c2a[3]);
      c2a[4]  = fmaf(B1.x, w2v[2], c2a[4]);
      c2a[5]  = fmaf(B1.y, w2v[2], c2a[5]);
      c2a[6]  = fmaf(B1.z, w2v[2], c2a[6]);
      c2a[7]  = fmaf(B1.w, w2v[2], c2a[7]);
      c2a[8]  = fmaf(B2.x, w2v[2], c2a[8]);
      c2a[9]  = fmaf(B2.y, w2v[3], c2a[9]);
      c2a[10] = fmaf(B2.z, w2v[3], c2a[10]);
      c2a[11] = fmaf(B2.w, w2v[3], c2a[11]);
      c2a[12] = fmaf(B3.x, w2v[3], c2a[12]);
      c2a[13] = fmaf(B3.y, w2v[3], c2a[13]);
      c2a[14] = fmaf(B3.z, w2v[3], c2a[14]);
      c2a[15] = fmaf(B3.w, w2v[3], c2a[15]);
    }
  }

  const float ism = 0.08838834764831845f;  // 1/sqrt(128)
  unsigned int pk1[8], pk2[8];
#pragma unroll
  for (int q = 0; q < 8; ++q) {
    pk1[q] = (unsigned)f2h(c1a[2 * q] * ism) | ((unsigned)f2h(c1a[2 * q + 1] * ism) << 16);
    pk2[q] = (unsigned)f2h(c2a[2 * q] * ism) | ((unsigned)f2h(c2a[2 * q + 1] * ism) << 16);
  }
  const size_t ob = (((size_t)IP * 1024 + n) * 128 + c) * 16;
  uint4* o1 = (uint4*)(c1H + ob);
  uint4* o2 = (uint4*)(c2H + ob);
  o1[0] = make_uint4(pk1[0], pk1[1], pk1[2], pk1[3]);
  o1[1] = make_uint4(pk1[4], pk1[5], pk1[6], pk1[7]);
  o2[0] = make_uint4(pk2[0], pk2[1], pk2[2], pk2[3]);
  o2[1] = make_uint4(pk2[4], pk2[5], pk2[6], pk2[7]);
}

__global__ __launch_bounds__(256, 4) void stage1_kernel(
    const float* __restrict__ x1, const float* __restrict__ x2,
    const float* __restrict__ W1, const float* __restrict__ W2,
    unsigned short* __restrict__ c1H, unsigned short* __restrict__ c2H)
{
  __shared__ float lds[2048];
  const int bid = blockIdx.x;
  const int ip = bid >> 9;
  const int nb = bid & 511;
  const int tid = threadIdx.x;
  if (ip == 0)      stage1_body<0>(nb, tid, lds, x1, x2, W1, W2, c1H, c2H);
  else if (ip == 1) stage1_body<1>(nb, tid, lds, x1, x2, W1, W2, c1H, c2H);
  else              stage1_body<2>(nb, tid, lds, x1, x2, W1, W2, c1H, c2H);
}

// ---------------------------------------------------------------------------
// K2: fused stages 2+3 (MFMA f16).  3072 blocks (ip = bid>>10, n = bid&1023),
// 256 threads = 4 waves; wave w owns c-rows 32w..32w+31 (2 m-tiles of 16).
// GEMM1: G[c][g] = C1[c][k16] x Yin[k16][g]   (16x16x32, K zero-padded)
// P = G1*G2 -> LDS (XOR-swizzled rows), GEMM2: Z[c][kout] = P x YowT
// zH layout: [ip][kout49][n][c] f16
// ---------------------------------------------------------------------------
__global__ __launch_bounds__(256, 3) void fused23_kernel(
    const unsigned short* __restrict__ c1H, const unsigned short* __restrict__ c2H,
    const unsigned short* __restrict__ YinH, const unsigned short* __restrict__ YowH,
    unsigned short* __restrict__ zH)
{
  __shared__ char Pl[32768];   // P[c=128][g=128] f16, byte = m*256 + (g*2 ^ ((m&7)<<4))
  const int bid = blockIdx.x;
  const int ip  = bid >> 10;
  const int n   = bid & 1023;
  const int tid = threadIdx.x;
  const int w    = tid >> 6;
  const int lane = tid & 63;
  const int lr   = lane & 15;
  const int lg   = lane >> 4;

  const short8 Z8 = {0, 0, 0, 0, 0, 0, 0, 0};

  // A-frags (c1,c2) for this wave's 2 m-tiles; K=16 padded to 32 (lanes lg>=2 zero)
  short8 a1[2], a2[2];
  const size_t cbase = ((size_t)ip * 1024 + n) * 128 * 16;
#pragma unroll
  for (int mti = 0; mti < 2; ++mti) {
    const int c = (2 * w + mti) * 16 + lr;
    a1[mti] = Z8; a2[mti] = Z8;
    if (lg < 2) {
      a1[mti] = *(const short8*)(c1H + cbase + (size_t)c * 16 + lg * 8);
      a2[mti] = *(const short8*)(c2H + cbase + (size_t)c * 16 + lg * 8);
    }
  }

  // ---- GEMM1 + P-write, two g-halves to bound register pressure ----
#pragma unroll
  for (int h = 0; h < 2; ++h) {
    short8 yb[4];
#pragma unroll
    for (int gq = 0; gq < 4; ++gq) {
      const int g = (h * 4 + gq) * 16 + lr;
      yb[gq] = Z8;
      if (lg < 2) yb[gq] = *(const short8*)(YinH + (size_t)g * 16 + lg * 8);
    }
    f32x4 G1[2][4], G2[2][4];
#pragma unroll
    for (int mti = 0; mti < 2; ++mti)
#pragma unroll
      for (int gq = 0; gq < 4; ++gq) {
        G1[mti][gq] = (f32x4){0.f, 0.f, 0.f, 0.f};
        G2[mti][gq] = (f32x4){0.f, 0.f, 0.f, 0.f};
        G1[mti][gq] = __builtin_amdgcn_mfma_f32_16x16x32_f16(a1[mti], yb[gq], G1[mti][gq], 0, 0, 0);
        G2[mti][gq] = __builtin_amdgcn_mfma_f32_16x16x32_f16(a2[mti], yb[gq], G2[mti][gq], 0, 0, 0);
      }
    // P = G1*G2 -> LDS (each wave writes only its own 32 rows)
#pragma unroll
    for (int mti = 0; mti < 2; ++mti)
#pragma unroll
      for (int gq = 0; gq < 4; ++gq) {
        const int g = (h * 4 + gq) * 16 + lr;
#pragma unroll
        for (int j = 0; j < 4; ++j) {
          const int m = (2 * w + mti) * 16 + lg * 4 + j;
          const float p = G1[mti][gq][j] * G2[mti][gq][j];
          *(unsigned short*)(Pl + m * 256 + ((g * 2) ^ ((m & 7) << 4))) = f2h(p);
        }
      }
  }
  __syncthreads();

  // ---- GEMM2: Z[c][kout] = P[c][g] x YowT[g][kout] ----
  short8 yw[4][4];   // [kout-tile][k-step]
#pragma unroll
  for (int kt = 0; kt < 4; ++kt)
#pragma unroll
    for (int ks = 0; ks < 4; ++ks)
      yw[kt][ks] = *(const short8*)(YowH + (size_t)(kt * 16 + lr) * 128 + ks * 32 + lg * 8);

  f32x4 Zc[2][4];
#pragma unroll
  for (int mti = 0; mti < 2; ++mti)
#pragma unroll
    for (int kt = 0; kt < 4; ++kt) Zc[mti][kt] = (f32x4){0.f, 0.f, 0.f, 0.f};

#pragma unroll
  for (int ks = 0; ks < 4; ++ks) {
    short8 ap[2];
#pragma unroll
    for (int mti = 0; mti < 2; ++mti) {
      const int m = (2 * w + mti) * 16 + lr;
      ap[mti] = *(const short8*)(Pl + m * 256 + ((ks * 64 + lg * 16) ^ ((m & 7) << 4)));
    }
#pragma unroll
    for (int mti = 0; mti < 2; ++mti)
#pragma unroll
      for (int kt = 0; kt < 4; ++kt)
        Zc[mti][kt] = __builtin_amdgcn_mfma_f32_16x16x32_f16(ap[mti], yw[kt][ks], Zc[mti][kt], 0, 0, 0);
  }

  // epilogue: zH[ip][kout][n][c] f16, 4 consecutive c per lane -> 8B store
#pragma unroll
  for (int mti = 0; mti < 2; ++mti)
#pragma unroll
    for (int kt = 0; kt < 4; ++kt) {
      const int kout = kt * 16 + lr;
      if (kout < 49) {
        const int c0 = (2 * w + mti) * 16 + lg * 4;
        uint2 v;
        v.x = (unsigned)f2h(Zc[mti][kt][0]) | ((unsigned)f2h(Zc[mti][kt][1]) << 16);
        v.y = (unsigned)f2h(Zc[mti][kt][2]) | ((unsigned)f2h(Zc[mti][kt][3]) << 16);
        *(uint2*)(zH + (((size_t)ip * 49 + kout) * 1024 + n) * 128 + c0) = v;
      }
    }
}

// ---------------------------------------------------------------------------
// K3: stage4 (MFMA f16).  1176 blocks: ip = bid/392; r = bid%392;
// w49 = r>>3 (=l^2+kk), nblk = r&7.  Block GEMM: 128n x 128d, K = 128c.
// out[n][ip*6272 + d*49 + w49] = (1/sqrt(C)) * sum_c zH[ip][w49][n][c]*WoT[ip][l][d][c]
// ---------------------------------------------------------------------------
__global__ __launch_bounds__(256, 3) void stage4_mfma(
    const unsigned short* __restrict__ zH, const unsigned short* __restrict__ WoTH,
    float* __restrict__ out)
{
  const int bid = blockIdx.x;
  const int ip  = bid / 392;
  const int r   = bid - ip * 392;
  const int w49 = r >> 3;
  const int nblk = r & 7;
  const int l   = lof_out(w49);
  const int tid = threadIdx.x;
  const int wv   = tid >> 6;
  const int lane = tid & 63;
  const int lr   = lane & 15;
  const int lg   = lane >> 4;

  const unsigned short* Ab = zH + (((size_t)ip * 49 + w49) * 1024 + nblk * 128) * 128;
  const unsigned short* Bb = WoTH + (size_t)(ip * 7 + l) * 128 * 128;

  f32x4 acc[2][8];
#pragma unroll
  for (int mti = 0; mti < 2; ++mti)
#pragma unroll
    for (int dt = 0; dt < 8; ++dt) acc[mti][dt] = (f32x4){0.f, 0.f, 0.f, 0.f};

#pragma unroll
  for (int ks = 0; ks < 4; ++ks) {
    short8 b[8], a[2];
#pragma unroll
    for (int dt = 0; dt < 8; ++dt)
      b[dt] = *(const short8*)(Bb + (size_t)(dt * 16 + lr) * 128 + ks * 32 + lg * 8);
#pragma unroll
    for (int mti = 0; mti < 2; ++mti)
      a[mti] = *(const short8*)(Ab + (size_t)((2 * wv + mti) * 16 + lr) * 128 + ks * 32 + lg * 8);
#pragma unroll
    for (int mti = 0; mti < 2; ++mti)
#pragma unroll
      for (int dt = 0; dt < 8; ++dt)
        acc[mti][dt] = __builtin_amdgcn_mfma_f32_16x16x32_f16(a[mti], b[dt], acc[mti][dt], 0, 0, 0);
  }

  const float isc = 0.08838834764831845f;  // 1/sqrt(128)
#pragma unroll
  for (int mti = 0; mti < 2; ++mti)
#pragma unroll
    for (int dt = 0; dt < 8; ++dt) {
      const int d = dt * 16 + lr;
#pragma unroll
      for (int j = 0; j < 4; ++j) {
        const int n = nblk * 128 + (2 * wv + mti) * 16 + lg * 4 + j;
        out[(size_t)n * 18816 + ip * 6272 + d * 49 + w49] = acc[mti][dt][j] * isc;
      }
    }
}

// ---------------------------------------------------------------------------
extern "C" void kernel_launch(void* const* d_in, const int* in_sizes, int n_in,
                              void* d_out, int out_size, void* d_ws, size_t ws_size,
                              hipStream_t stream)
{
  const float* x1 = (const float*)d_in[0];   // (1024,128,2,16)
  const float* x2 = (const float*)d_in[1];   // (1024,128,2,16)
  const float* W1 = (const float*)d_in[2];   // (3,4,128,128)
  const float* W2 = (const float*)d_in[3];   // (3,4,128,128)
  const float* Wo = (const float*)d_in[4];   // (3,7,128,128)
  float* out = (float*)d_out;                // (1024, 3*128*49)

  char* ws = (char*)d_ws;
  unsigned short* YinH = (unsigned short*)(ws);                    //   4 KB
  unsigned short* YowH = (unsigned short*)(ws + 16384);            //  16 KB
  unsigned short* WoTH = (unsigned short*)(ws + 49152);            // 672 KB
  unsigned short* c1H  = (unsigned short*)(ws + (1u << 20));       // 12.6 MB
  unsigned short* c2H  = (unsigned short*)(ws + (1u << 24));       // 12.6 MB
  unsigned short* zH   = (unsigned short*)(ws + (1u << 25));       // 38.5 MB

  tables_kernel<<<1, 128, 0, stream>>>(YinH, YowH);
  prep_wot<<<1344, 256, 0, stream>>>(Wo, WoTH);
  stage1_kernel<<<1536, 256, 0, stream>>>(x1, x2, W1, W2, c1H, c2H);
  fused23_kernel<<<3072, 256, 0, stream>>>(c1H, c2H, YinH, YowH, zH);
  stage4_mfma<<<1176, 256, 0, stream>>>(zH, WoTH, out);
}